// Round 8
// baseline (1453.514 us; speedup 1.0000x reference)
//
#include <hip/hip_runtime.h>
#include <cstdint>
#include <cstddef>

// Round 8: unclamp registers (amdgpu_waves_per_eu(2,2) — LDS already caps us
// at 1 block/CU, so 2 waves/EU is the truth and the allocator gets ~512
// unified regs/wave), then one-phase-lookahead 4-phase/tile schedule:
//   phi1: MFMA Q00(a0,b0) | read a1,b1(bufP)   | vm(0) | BAR
//   phi2: MFMA Q01(a0,b1) | read nextA0(bufQ)  | BAR
//   phi3: MFMA Q10(a1,b0) | read nextB0(bufQ) | stage A(t+2)->bufP | BAR
//   phi4: MFMA Q11(a1,b1) | stage B(t+2)->bufP | BAR
// Every MFMA's operands are read >=1 phase early; stages are 2-3 phases
// ahead of their reads; vm(0) drains only >=1-phase-old loads.
// y = x_bf16 @ (w*bf16(scale))_bf16^T + bias  (x_dq == x exactly: pow2 scales)

typedef __attribute__((ext_vector_type(8))) __bf16 bf16x8;
typedef __attribute__((ext_vector_type(4))) float f32x4;

__device__ __forceinline__ unsigned short bf16rn(float f) {
  unsigned u = __builtin_bit_cast(unsigned, f);
  u = (u + 0x7FFFu + ((u >> 16) & 1u)) >> 16;
  return (unsigned short)u;
}
__device__ __forceinline__ float bf16tof(unsigned short h) {
  unsigned u = ((unsigned)h) << 16;
  return __builtin_bit_cast(float, u);
}
__device__ __forceinline__ void gload_lds16(const void* g, void* l) {
  __builtin_amdgcn_global_load_lds(
      (const __attribute__((address_space(1))) unsigned int*)g,
      (__attribute__((address_space(3))) unsigned int*)l, 16, 0, 0);
}

// ---------------- Phase A: fused prep (x->bf16, w*scale->bf16) -------------

__global__ __launch_bounds__(256) void k_prep(
    const float* __restrict__ x, const float* __restrict__ w,
    const float* __restrict__ sc, unsigned short* __restrict__ xb,
    unsigned short* __restrict__ wb, int K, int nblk, int blk,
    int n8x, int n8w) {
  int t = blockIdx.x * 256 + threadIdx.x;
  if (t < n8x) {
    const float4* p = (const float4*)x + (size_t)t * 2;
    float4 a = p[0], b = p[1];
    uint4 o;
    o.x = (unsigned)bf16rn(a.x) | ((unsigned)bf16rn(a.y) << 16);
    o.y = (unsigned)bf16rn(a.z) | ((unsigned)bf16rn(a.w) << 16);
    o.z = (unsigned)bf16rn(b.x) | ((unsigned)bf16rn(b.y) << 16);
    o.w = (unsigned)bf16rn(b.z) | ((unsigned)bf16rn(b.w) << 16);
    ((uint4*)xb)[t] = o;
  } else if (t - n8x < n8w) {
    int tw = t - n8x;
    size_t base = (size_t)tw * 8;
    int o_row = (int)(base / (size_t)K);
    int k = (int)(base % (size_t)K);
    float s = bf16tof(bf16rn(sc[(size_t)o_row * nblk + k / blk]));
    const float4* p = (const float4*)w + (size_t)tw * 2;
    float4 a = p[0], b = p[1];
    uint4 o;
    o.x = (unsigned)bf16rn(a.x * s) | ((unsigned)bf16rn(a.y * s) << 16);
    o.y = (unsigned)bf16rn(a.z * s) | ((unsigned)bf16rn(a.w * s) << 16);
    o.z = (unsigned)bf16rn(b.x * s) | ((unsigned)bf16rn(b.y * s) << 16);
    o.w = (unsigned)bf16rn(b.z * s) | ((unsigned)bf16rn(b.w * s) << 16);
    ((uint4*)wb)[tw] = o;
  }
}

// ---------------- Phase B: 256^2 lookahead GEMM ----------------------------
// C[M][N] = A[M][K]*B[N][K]^T + bias. 512 thr = 8 waves (2Mx4N).
// LDS 128 KiB: 2 bufs x (A[256][64] + B[256][64]) bf16, XOR-swizzled
// (byte ^= (row&7)<<4, inverse-applied on global source, rule 21).

#define BM 256
#define BN 256
#define BK 64

#define BARF()                                  \
  do {                                          \
    __builtin_amdgcn_s_barrier();               \
    asm volatile("" ::: "memory");              \
    __builtin_amdgcn_sched_barrier(0);          \
  } while (0)
#define WAIT_VM(n) asm volatile("s_waitcnt vmcnt(" #n ")" ::: "memory")
#define PRIO(p) __builtin_amdgcn_s_setprio(p)

#define STG_A(buf, q, tile)                                               \
  gload_lds16(Ag + (size_t)(q) * 64 * Ks + (size_t)(tile) * BK,           \
              smem + (buf) * 65536 + (q) * 8192 + tid16)
#define STG_B(buf, q, tile)                                               \
  gload_lds16(Bg + (size_t)(q) * 64 * Ks + (size_t)(tile) * BK,           \
              smem + (buf) * 65536 + 32768 + (q) * 8192 + tid16)

#define READ_A(arr, buf, qm)                                              \
  _Pragma("unroll") for (int i_ = 0; i_ < 4; ++i_) {                      \
    arr[i_][0] = *(const bf16x8*)(smem + (buf) * 65536 +                  \
        (wr * 128 + (qm) * 64 + i_ * 16 + lr) * 128 + ko0);               \
    arr[i_][1] = *(const bf16x8*)(smem + (buf) * 65536 +                  \
        (wr * 128 + (qm) * 64 + i_ * 16 + lr) * 128 + ko1);               \
  }
#define READ_B(arr, buf, qn)                                              \
  _Pragma("unroll") for (int j_ = 0; j_ < 2; ++j_) {                      \
    arr[j_][0] = *(const bf16x8*)(smem + (buf) * 65536 + 32768 +          \
        (wc * 64 + (qn) * 32 + j_ * 16 + lr) * 128 + ko0);                \
    arr[j_][1] = *(const bf16x8*)(smem + (buf) * 65536 + 32768 +          \
        (wc * 64 + (qn) * 32 + j_ * 16 + lr) * 128 + ko1);                \
  }
#define MFMA_Q(qm, qn, aarr, barr)                                        \
  _Pragma("unroll") for (int kk_ = 0; kk_ < 2; ++kk_)                     \
  _Pragma("unroll") for (int i_ = 0; i_ < 4; ++i_)                        \
  _Pragma("unroll") for (int j_ = 0; j_ < 2; ++j_)                        \
    acc[(qm) * 4 + i_][(qn) * 2 + j_] =                                   \
        __builtin_amdgcn_mfma_f32_16x16x32_bf16(                          \
            aarr[i_][kk_], barr[j_][kk_],                                 \
            acc[(qm) * 4 + i_][(qn) * 2 + j_], 0, 0, 0);

// One tile-block: tile lives in bufP; lookahead reads from bufQ (tile+1);
// stages tile tSt (= tile+2) into bufP at phi3/phi4.
#define BLOCK4(P, Q, aCur, bCur, aS, bS, aNxt, bNxt, tSt, DOST, DONXT)    \
  do {                                                                    \
    /* phi1 */                                                            \
    READ_A(aS, P, 1); READ_B(bS, P, 1);                                   \
    PRIO(1); MFMA_Q(0, 0, aCur, bCur); PRIO(0);                           \
    WAIT_VM(0);                                                           \
    BARF();                                                               \
    /* phi2 */                                                            \
    if (DONXT) { READ_A(aNxt, Q, 0); }                                    \
    PRIO(1); MFMA_Q(0, 1, aCur, bS); PRIO(0);                             \
    BARF();                                                               \
    /* phi3 */                                                            \
    if (DOST) { STG_A(P, 0, tSt); STG_A(P, 1, tSt);                       \
                STG_A(P, 2, tSt); STG_A(P, 3, tSt); }                     \
    if (DONXT) { READ_B(bNxt, Q, 0); }                                    \
    PRIO(1); MFMA_Q(1, 0, aS, bCur); PRIO(0);                             \
    BARF();                                                               \
    /* phi4 */                                                            \
    if (DOST) { STG_B(P, 0, tSt); STG_B(P, 1, tSt);                       \
                STG_B(P, 2, tSt); STG_B(P, 3, tSt); }                     \
    PRIO(1); MFMA_Q(1, 1, aS, bS); PRIO(0);                               \
    BARF();                                                               \
  } while (0)

__global__ __launch_bounds__(512)
__attribute__((amdgpu_waves_per_eu(2, 2)))
void k_gemm256(
    const unsigned short* __restrict__ A, const unsigned short* __restrict__ B,
    const float* __restrict__ bias, float* __restrict__ C,
    int M, int N, int K) {
  extern __shared__ __align__(16) char smem[];

  const int nbn = N / BN;
  const int nwg = gridDim.x;
  int bid = blockIdx.x;
  int wg = bid;
  if ((nwg & 7) == 0) wg = (bid & 7) * (nwg >> 3) + (bid >> 3);  // T1
  const int m0 = (wg / nbn) * BM;
  const int n0 = (wg % nbn) * BN;

  const int tid = threadIdx.x;
  const int lane = tid & 63;
  const int wid = tid >> 6;
  const int wr = wid >> 2;
  const int wc = wid & 3;
  const int lr = lane & 15;
  const int ko0 = (((lane >> 4) * 16) ^ ((lane & 7) << 4));
  const int ko1 = ((64 | ((lane >> 4) * 16)) ^ ((lane & 7) << 4));
  const int tid16 = tid * 16;

  const int srow = tid >> 3;
  const int sgran = (tid & 7) ^ (srow & 7);  // inverse swizzle on source
  const size_t Ks = (size_t)K;
  const unsigned short* Ag = A + (size_t)(m0 + srow) * Ks + sgran * 8;
  const unsigned short* Bg = B + (size_t)(n0 + srow) * Ks + sgran * 8;

  f32x4 acc[8][4] = {};
  bf16x8 aP[4][2], aQ[4][2], aS[4][2];
  bf16x8 bP[2][2], bQ[2][2], bS[2][2];

  const int NT = K / BK;      // even (launcher guards K % 128 == 0)
  const int NITER = NT / 2;

  // prologue: t0 -> buf0 (8 loads), t1 -> buf1 (8 loads); wait t0; read
  // first block's Q00 operands (aP,bP).
  STG_A(0, 0, 0); STG_A(0, 1, 0); STG_A(0, 2, 0); STG_A(0, 3, 0);
  STG_B(0, 0, 0); STG_B(0, 1, 0); STG_B(0, 2, 0); STG_B(0, 3, 0);
  STG_A(1, 0, 1); STG_A(1, 1, 1); STG_A(1, 2, 1); STG_A(1, 3, 1);
  STG_B(1, 0, 1); STG_B(1, 1, 1); STG_B(1, 2, 1); STG_B(1, 3, 1);
  WAIT_VM(8);
  BARF();
  READ_A(aP, 0, 0);
  READ_B(bP, 0, 0);

  for (int it = 0; it < NITER; ++it) {
    const int t = 2 * it;
    const bool s2 = (t + 2) < NT;   // stage t+2; also next-reads for block2
    const bool s3 = (t + 3) < NT;   // stage t+3
    // even tile t: bufP=0, lookahead bufQ=1 (tile t+1 always exists)
    BLOCK4(0, 1, aP, bP, aS, bS, aQ, bQ, t + 2, s2, true);
    // odd tile t+1: bufP=1, lookahead bufQ=0 (tile t+2, if any)
    BLOCK4(1, 0, aQ, bQ, aS, bS, aP, bP, t + 3, s3, s2);
  }

  // epilogue: row-burst; col=lane&15, row=(lane>>4)*4+r per frag
  const int col0 = n0 + wc * 64 + (lane & 15);
  const int row0 = m0 + wr * 128 + ((lane >> 4) << 2);
  float bj[4];
#pragma unroll
  for (int j = 0; j < 4; ++j) bj[j] = bias[col0 + j * 16];
#pragma unroll
  for (int i = 0; i < 8; ++i) {
#pragma unroll
    for (int r = 0; r < 4; ++r) {
      const size_t ro = (size_t)(row0 + i * 16 + r) * N;
#pragma unroll
      for (int j = 0; j < 4; ++j) {
        C[ro + col0 + j * 16] = acc[i][j][r] + bj[j];
      }
    }
  }
}

// ---------------- fallback (exact f32) ----------------

__global__ __launch_bounds__(256) void k_fallback(
    const float* __restrict__ x, const float* __restrict__ w,
    const float* __restrict__ sc, const float* __restrict__ bias,
    float* __restrict__ out, int T, int O, int K, int nblk, int blk) {
  long long idx = (long long)blockIdx.x * 256 + threadIdx.x;
  if (idx >= (long long)T * O) return;
  int row = (int)(idx / O), col = (int)(idx % O);
  const float* xr = x + (size_t)row * K;
  const float* wr = w + (size_t)col * K;
  const float* sr = sc + (size_t)col * nblk;
  float acc = 0.f;
  for (int b = 0; b < nblk; ++b) {
    float s = bf16tof(bf16rn(sr[b]));
    float part = 0.f;
    for (int k = 0; k < blk; k += 4) {
      float4 xa = *(const float4*)(xr + b * blk + k);
      float4 wa = *(const float4*)(wr + b * blk + k);
      part += xa.x * wa.x + xa.y * wa.y + xa.z * wa.z + xa.w * wa.w;
    }
    acc += part * s;
  }
  out[idx] = acc + bias[col];
}

extern "C" void kernel_launch(void* const* d_in, const int* in_sizes, int n_in,
                              void* d_out, int out_size, void* d_ws, size_t ws_size,
                              hipStream_t stream) {
  const float* x = (const float*)d_in[0];
  const float* w = (const float*)d_in[1];
  const float* sc = (const float*)d_in[2];
  const float* bias = (const float*)d_in[3];
  float* out = (float*)d_out;

  const int x_n = in_sizes[0];
  const int w_n = in_sizes[1];
  const int s_n = in_sizes[2];
  const int O = in_sizes[3];
  const int K = w_n / O;
  const int T = x_n / K;
  const int nblk = s_n / O;
  const int blk = K / nblk;

  const size_t need = (size_t)x_n * 2 + (size_t)w_n * 2;
  const bool tiled_ok = ws_size >= need && (K % (2 * BK)) == 0 &&
                        (T % BM) == 0 && (O % BN) == 0 && (blk % 8) == 0 &&
                        K >= 2 * BK;

  if (tiled_ok) {
    unsigned short* xb = (unsigned short*)d_ws;
    unsigned short* wb = xb + (size_t)x_n;
    int n8x = x_n / 8, n8w = w_n / 8;
    int nprep = n8x + n8w;
    k_prep<<<(nprep + 255) / 256, 256, 0, stream>>>(x, w, sc, xb, wb, K, nblk,
                                                    blk, n8x, n8w);
    hipFuncSetAttribute((const void*)k_gemm256,
                        hipFuncAttributeMaxDynamicSharedMemorySize, 131072);
    dim3 grid((T / BM) * (O / BN));
    k_gemm256<<<grid, 512, 131072, stream>>>(xb, wb, bias, out, T, O, K);
  } else {
    long long total = (long long)T * O;
    dim3 grid((unsigned)((total + 255) / 256));
    k_fallback<<<grid, 256, 0, stream>>>(x, w, sc, bias, out, T, O, K, nblk, blk);
  }
}

// Round 9
// 284.762 us; speedup vs baseline: 5.1043x; 5.1043x over previous
//
#include <hip/hip_runtime.h>
#include <cstdint>
#include <cstddef>

// Round 9: faithful m201 8-phase port. Per phase:
//   {ds_reads (0/4/8/12) || stage 2 gload_lds} -> [lgkm(8) if 12 reads]
//   -> BAR -> lgkm(0)+schedbar -> setprio(1) 16 MFMA setprio(0) -> BAR
// Carried operands: 24 reads/K-tile (12/4/8/0). vmcnt(6) ONLY at phi4/phi8
// (3 stage-phases in flight). Region ledger (quarter-granular, B staged as
// quarter-pairs {0,2}/{1,3}): stage slots phi2..phi5 for buf0(t+2) =
// Aq0,B02,Aq1,B13; phi6,phi7,phi8,phi1' for buf1(t+3) = Aq0,B02,Aq1,B13.
// Every stage lands >=3 phases before its guarded read; every stage is >=1
// barrier after its region's last ds_read. 256-reg/wave cap respected:
// peak operand liveness 48 VGPR + addressing, acc 128 AGPR.
// y = x_bf16 @ (w*bf16(scale))_bf16^T + bias  (x_dq == x exactly: pow2 scales)

typedef __attribute__((ext_vector_type(8))) __bf16 bf16x8;
typedef __attribute__((ext_vector_type(4))) float f32x4;

__device__ __forceinline__ unsigned short bf16rn(float f) {
  unsigned u = __builtin_bit_cast(unsigned, f);
  u = (u + 0x7FFFu + ((u >> 16) & 1u)) >> 16;
  return (unsigned short)u;
}
__device__ __forceinline__ float bf16tof(unsigned short h) {
  unsigned u = ((unsigned)h) << 16;
  return __builtin_bit_cast(float, u);
}
__device__ __forceinline__ void gload_lds16(const void* g, void* l) {
  __builtin_amdgcn_global_load_lds(
      (const __attribute__((address_space(1))) unsigned int*)g,
      (__attribute__((address_space(3))) unsigned int*)l, 16, 0, 0);
}

// ---------------- Phase A: fused prep (x->bf16, w*scale->bf16) -------------

__global__ __launch_bounds__(256) void k_prep(
    const float* __restrict__ x, const float* __restrict__ w,
    const float* __restrict__ sc, unsigned short* __restrict__ xb,
    unsigned short* __restrict__ wb, int K, int nblk, int blk,
    int n8x, int n8w) {
  int t = blockIdx.x * 256 + threadIdx.x;
  if (t < n8x) {
    const float4* p = (const float4*)x + (size_t)t * 2;
    float4 a = p[0], b = p[1];
    uint4 o;
    o.x = (unsigned)bf16rn(a.x) | ((unsigned)bf16rn(a.y) << 16);
    o.y = (unsigned)bf16rn(a.z) | ((unsigned)bf16rn(a.w) << 16);
    o.z = (unsigned)bf16rn(b.x) | ((unsigned)bf16rn(b.y) << 16);
    o.w = (unsigned)bf16rn(b.z) | ((unsigned)bf16rn(b.w) << 16);
    ((uint4*)xb)[t] = o;
  } else if (t - n8x < n8w) {
    int tw = t - n8x;
    size_t base = (size_t)tw * 8;
    int o_row = (int)(base / (size_t)K);
    int k = (int)(base % (size_t)K);
    float s = bf16tof(bf16rn(sc[(size_t)o_row * nblk + k / blk]));
    const float4* p = (const float4*)w + (size_t)tw * 2;
    float4 a = p[0], b = p[1];
    uint4 o;
    o.x = (unsigned)bf16rn(a.x * s) | ((unsigned)bf16rn(a.y * s) << 16);
    o.y = (unsigned)bf16rn(a.z * s) | ((unsigned)bf16rn(a.w * s) << 16);
    o.z = (unsigned)bf16rn(b.x * s) | ((unsigned)bf16rn(b.y * s) << 16);
    o.w = (unsigned)bf16rn(b.z * s) | ((unsigned)bf16rn(b.w * s) << 16);
    ((uint4*)wb)[tw] = o;
  }
}

// ---------------- Phase B: 256^2 m201-style 8-phase GEMM -------------------
// C[M][N] = A[M][K]*B[N][K]^T + bias. 512 thr = 8 waves (2Mx4N).
// LDS 128 KiB: 2 bufs x (A[256][64] + B[256][64]) bf16, XOR-swizzled
// (byte ^= (row&7)<<4, inverse-applied on global source, rule 21).

#define BM 256
#define BN 256
#define BK 64

#define BARF()                                  \
  do {                                          \
    __builtin_amdgcn_s_barrier();               \
    asm volatile("" ::: "memory");              \
    __builtin_amdgcn_sched_barrier(0);          \
  } while (0)
#define WAIT_VM(n) asm volatile("s_waitcnt vmcnt(" #n ")" ::: "memory")
#define WAIT_LGKM(n) asm volatile("s_waitcnt lgkmcnt(" #n ")" ::: "memory")
#define SCHEDB() __builtin_amdgcn_sched_barrier(0)
#define PRIO(p) __builtin_amdgcn_s_setprio(p)

#define STG_A(buf, q, tile)                                               \
  gload_lds16(Ag + (size_t)(q) * 64 * Ks + (size_t)(tile) * BK,           \
              smem + (buf) * 65536 + (q) * 8192 + tid16)
#define STG_B(buf, q, tile)                                               \
  gload_lds16(Bg + (size_t)(q) * 64 * Ks + (size_t)(tile) * BK,           \
              smem + (buf) * 65536 + 32768 + (q) * 8192 + tid16)

#define READ_A(arr, buf, qm)                                              \
  _Pragma("unroll") for (int i_ = 0; i_ < 4; ++i_) {                      \
    arr[i_][0] = *(const bf16x8*)(smem + (buf) * 65536 +                  \
        (wr * 128 + (qm) * 64 + i_ * 16 + lr) * 128 + ko0);               \
    arr[i_][1] = *(const bf16x8*)(smem + (buf) * 65536 +                  \
        (wr * 128 + (qm) * 64 + i_ * 16 + lr) * 128 + ko1);               \
  }
#define READ_B(arr, buf, qn)                                              \
  _Pragma("unroll") for (int j_ = 0; j_ < 2; ++j_) {                      \
    arr[j_][0] = *(const bf16x8*)(smem + (buf) * 65536 + 32768 +          \
        (wc * 64 + (qn) * 32 + j_ * 16 + lr) * 128 + ko0);                \
    arr[j_][1] = *(const bf16x8*)(smem + (buf) * 65536 + 32768 +          \
        (wc * 64 + (qn) * 32 + j_ * 16 + lr) * 128 + ko1);                \
  }
#define MFMA_Q(qm, qn, aarr, barr)                                        \
  _Pragma("unroll") for (int kk_ = 0; kk_ < 2; ++kk_)                     \
  _Pragma("unroll") for (int i_ = 0; i_ < 4; ++i_)                        \
  _Pragma("unroll") for (int j_ = 0; j_ < 2; ++j_)                        \
    acc[(qm) * 4 + i_][(qn) * 2 + j_] =                                   \
        __builtin_amdgcn_mfma_f32_16x16x32_bf16(                          \
            aarr[i_][kk_], barr[j_][kk_],                                 \
            acc[(qm) * 4 + i_][(qn) * 2 + j_], 0, 0, 0);

__global__ __launch_bounds__(512, 2) void k_gemm256(
    const unsigned short* __restrict__ A, const unsigned short* __restrict__ B,
    const float* __restrict__ bias, float* __restrict__ C,
    int M, int N, int K) {
  extern __shared__ __align__(16) char smem[];

  const int nbn = N / BN;
  const int nwg = gridDim.x;
  int bid = blockIdx.x;
  int wg = bid;
  if ((nwg & 7) == 0) wg = (bid & 7) * (nwg >> 3) + (bid >> 3);  // T1
  const int m0 = (wg / nbn) * BM;
  const int n0 = (wg % nbn) * BN;

  const int tid = threadIdx.x;
  const int lane = tid & 63;
  const int wid = tid >> 6;
  const int wr = wid >> 2;
  const int wc = wid & 3;
  const int lr = lane & 15;
  const int ko0 = (((lane >> 4) * 16) ^ ((lane & 7) << 4));
  const int ko1 = ((64 | ((lane >> 4) * 16)) ^ ((lane & 7) << 4));
  const int tid16 = tid * 16;

  const int srow = tid >> 3;
  const int sgran = (tid & 7) ^ (srow & 7);  // inverse swizzle on source
  const size_t Ks = (size_t)K;
  const unsigned short* Ag = A + (size_t)(m0 + srow) * Ks + sgran * 8;
  const unsigned short* Bg = B + (size_t)(n0 + srow) * Ks + sgran * 8;

  f32x4 acc[8][4] = {};
  bf16x8 a0[4][2], a1[4][2], b0[2][2], b1[2][2];

  const int NT = K / BK;
  const int NITER = NT / 2;

  // prologue: t0 full -> buf0 (8 loads); t1 partial -> buf1: Aq0,B{0,2},Aq1
  // (6 loads; B{1,3}(t+1) staged at phi1 of iter 0). vm(6): t0 landed.
  STG_A(0, 0, 0); STG_A(0, 2, 0); STG_A(0, 1, 0); STG_A(0, 3, 0);
  STG_B(0, 0, 0); STG_B(0, 2, 0); STG_B(0, 1, 0); STG_B(0, 3, 0);
  STG_A(1, 0, 1); STG_A(1, 2, 1);
  STG_B(1, 0, 1); STG_B(1, 2, 1);
  STG_A(1, 1, 1); STG_A(1, 3, 1);
  WAIT_VM(6);
  BARF();

  for (int it = 0; it < NITER; ++it) {
    const int t = 2 * it;
    const bool s2 = (t + 2) < NT;
    const bool s3 = (t + 3) < NT;
    // phi1: reads a0,b0(buf0) [12]; stage B{1,3}(buf1,t+1); MFMA Q00
    READ_A(a0, 0, 0); READ_B(b0, 0, 0);
    STG_B(1, 1, t + 1); STG_B(1, 3, t + 1);
    SCHEDB(); WAIT_LGKM(8);
    BARF();
    WAIT_LGKM(0); SCHEDB();
    PRIO(1); MFMA_Q(0, 0, a0, b0); PRIO(0);
    BARF();
    // phi2: reads b1(buf0) [4]; stage Aq0(buf0,t+2); MFMA Q01
    READ_B(b1, 0, 1);
    if (s2) { STG_A(0, 0, t + 2); STG_A(0, 2, t + 2); }
    SCHEDB();
    BARF();
    WAIT_LGKM(0); SCHEDB();
    PRIO(1); MFMA_Q(0, 1, a0, b1); PRIO(0);
    BARF();
    // phi3: reads a1(buf0) [8]; stage B{0,2}(buf0,t+2); MFMA Q10
    READ_A(a1, 0, 1);
    if (s2) { STG_B(0, 0, t + 2); STG_B(0, 2, t + 2); }
    SCHEDB();
    BARF();
    WAIT_LGKM(0); SCHEDB();
    PRIO(1); MFMA_Q(1, 0, a1, b0); PRIO(0);
    BARF();
    // phi4: stage Aq1(buf0,t+2); vm(6) -> t+1 fully landed; MFMA Q11
    if (s2) { STG_A(0, 1, t + 2); STG_A(0, 3, t + 2); WAIT_VM(6); }
    else    { WAIT_VM(0); }
    BARF();
    PRIO(1); MFMA_Q(1, 1, a1, b1); PRIO(0);
    BARF();
    // phi5: reads a0,b0(buf1) [12]; stage B{1,3}(buf0,t+2); MFMA Q00
    READ_A(a0, 1, 0); READ_B(b0, 1, 0);
    if (s2) { STG_B(0, 1, t + 2); STG_B(0, 3, t + 2); }
    SCHEDB(); WAIT_LGKM(8);
    BARF();
    WAIT_LGKM(0); SCHEDB();
    PRIO(1); MFMA_Q(0, 0, a0, b0); PRIO(0);
    BARF();
    // phi6: reads b1(buf1) [4]; stage Aq0(buf1,t+3); MFMA Q01
    READ_B(b1, 1, 1);
    if (s3) { STG_A(1, 0, t + 3); STG_A(1, 2, t + 3); }
    SCHEDB();
    BARF();
    WAIT_LGKM(0); SCHEDB();
    PRIO(1); MFMA_Q(0, 1, a0, b1); PRIO(0);
    BARF();
    // phi7: reads a1(buf1) [8]; stage B{0,2}(buf1,t+3); MFMA Q10
    READ_A(a1, 1, 1);
    if (s3) { STG_B(1, 0, t + 3); STG_B(1, 2, t + 3); }
    SCHEDB();
    BARF();
    WAIT_LGKM(0); SCHEDB();
    PRIO(1); MFMA_Q(1, 0, a1, b0); PRIO(0);
    BARF();
    // phi8: stage Aq1(buf1,t+3); vm(6) -> t+2 fully landed; MFMA Q11
    if (s3) { STG_A(1, 1, t + 3); STG_A(1, 3, t + 3); WAIT_VM(6); }
    else if (s2) { WAIT_VM(0); }
    BARF();
    PRIO(1); MFMA_Q(1, 1, a1, b1); PRIO(0);
    BARF();
  }

  // epilogue: row-burst; col=lane&15, row=(lane>>4)*4+r per frag
  const int col0 = n0 + wc * 64 + (lane & 15);
  const int row0 = m0 + wr * 128 + ((lane >> 4) << 2);
  float bj[4];
#pragma unroll
  for (int j = 0; j < 4; ++j) bj[j] = bias[col0 + j * 16];
#pragma unroll
  for (int i = 0; i < 8; ++i) {
#pragma unroll
    for (int r = 0; r < 4; ++r) {
      const size_t ro = (size_t)(row0 + i * 16 + r) * N;
#pragma unroll
      for (int j = 0; j < 4; ++j) {
        C[ro + col0 + j * 16] = acc[i][j][r] + bj[j];
      }
    }
  }
}

// ---------------- fallback (exact f32) ----------------

__global__ __launch_bounds__(256) void k_fallback(
    const float* __restrict__ x, const float* __restrict__ w,
    const float* __restrict__ sc, const float* __restrict__ bias,
    float* __restrict__ out, int T, int O, int K, int nblk, int blk) {
  long long idx = (long long)blockIdx.x * 256 + threadIdx.x;
  if (idx >= (long long)T * O) return;
  int row = (int)(idx / O), col = (int)(idx % O);
  const float* xr = x + (size_t)row * K;
  const float* wr = w + (size_t)col * K;
  const float* sr = sc + (size_t)col * nblk;
  float acc = 0.f;
  for (int b = 0; b < nblk; ++b) {
    float s = bf16tof(bf16rn(sr[b]));
    float part = 0.f;
    for (int k = 0; k < blk; k += 4) {
      float4 xa = *(const float4*)(xr + b * blk + k);
      float4 wa = *(const float4*)(wr + b * blk + k);
      part += xa.x * wa.x + xa.y * wa.y + xa.z * wa.z + xa.w * wa.w;
    }
    acc += part * s;
  }
  out[idx] = acc + bias[col];
}

extern "C" void kernel_launch(void* const* d_in, const int* in_sizes, int n_in,
                              void* d_out, int out_size, void* d_ws, size_t ws_size,
                              hipStream_t stream) {
  const float* x = (const float*)d_in[0];
  const float* w = (const float*)d_in[1];
  const float* sc = (const float*)d_in[2];
  const float* bias = (const float*)d_in[3];
  float* out = (float*)d_out;

  const int x_n = in_sizes[0];
  const int w_n = in_sizes[1];
  const int s_n = in_sizes[2];
  const int O = in_sizes[3];
  const int K = w_n / O;
  const int T = x_n / K;
  const int nblk = s_n / O;
  const int blk = K / nblk;

  const size_t need = (size_t)x_n * 2 + (size_t)w_n * 2;
  const bool tiled_ok = ws_size >= need && (K % (2 * BK)) == 0 &&
                        (T % BM) == 0 && (O % BN) == 0 && (blk % 8) == 0 &&
                        K >= 2 * BK;

  if (tiled_ok) {
    unsigned short* xb = (unsigned short*)d_ws;
    unsigned short* wb = xb + (size_t)x_n;
    int n8x = x_n / 8, n8w = w_n / 8;
    int nprep = n8x + n8w;
    k_prep<<<(nprep + 255) / 256, 256, 0, stream>>>(x, w, sc, xb, wb, K, nblk,
                                                    blk, n8x, n8w);
    hipFuncSetAttribute((const void*)k_gemm256,
                        hipFuncAttributeMaxDynamicSharedMemorySize, 131072);
    dim3 grid((T / BM) * (O / BN));
    k_gemm256<<<grid, 512, 131072, stream>>>(xb, wb, bias, out, T, O, K);
  } else {
    long long total = (long long)T * O;
    dim3 grid((unsigned)((total + 255) / 256));
    k_fallback<<<grid, 256, 0, stream>>>(x, w, sc, bias, out, T, O, K, nblk, blk);
  }
}